// Round 7
// baseline (439.627 us; speedup 1.0000x reference)
//
#include <hip/hip_runtime.h>
#include <hip/hip_bf16.h>
#include <stdint.h>

#define QL 1024
#define KL 1024
#define HM 64
#define DD 128
#define SM_SCALE 0.08838834764831845f
#define LDP 136   // bf16 row stride for Ks: 272B rows (16B-aligned)
#define OSP 36    // f32 row stride for Os: 144B rows (16B-aligned)

typedef __bf16 bf16x8 __attribute__((ext_vector_type(8)));
typedef __bf16 bf16x4 __attribute__((ext_vector_type(4)));
typedef float floatx4 __attribute__((ext_vector_type(4)));
typedef float floatx4u __attribute__((ext_vector_type(4), aligned(4)));

// =====================================================================
// qk7 = qk6 + occupancy (the round-5 lever). Resubmission — round-6 run
// died on container acquisition (infra), kernel never executed.
//   Grid 512 -> 1024 blocks: block = (g, qt in 0..7 [128 q], kh in 0..1
//   [512 k]); K-iter tile 64 -> 32 rows so LDS = 17.4 (Ks dbuf) + 18 (Os)
//   = ~36 KB -> 4 blocks/CU (was 2). 16 waves/CU hide the per-iteration
//   barrier's store/load drain (qk6's residual stall: at 2 blocks/CU the
//   vmcnt(0) drain parked the whole CU).
//   - __launch_bounds__(256,4): cap 128 VGPR so all 16 waves resident.
//   - Q in registers whole kernel (64 VGPR); K cooperatively staged,
//     loads for kt+1 issued early; Os wave-private park -> mask/store
//     instructions cover 8 rows x 128 B contiguous (no 16-seg scatter).
//   - Cached stores (NT = 1.43x write ampl, qk4). XCD-chunked mapping:
//     bid&7 = XCD, 8 g's per XCD -> K slices + mask hot in L2/L3.
//   - sink column fused into kh==1 blocks.
// =====================================================================
__global__ __launch_bounds__(256, 4)
void qk7_kernel(const float* __restrict__ Qg, const float* __restrict__ Kg,
                const float* __restrict__ mask, const float* __restrict__ sinks,
                float* __restrict__ out)
{
    const int bid   = blockIdx.x;        // 0..1023
    const int xcd   = bid & 7;
    const int inner = bid >> 3;          // 0..127
    const int g     = xcd * 8 + (inner >> 4);
    const int rest  = inner & 15;
    const int qt    = rest >> 1;         // 0..7
    const int kh    = rest & 1;          // 0..1 (k half)

    __shared__ __bf16 Ks[2][32][LDP];    // 17.4 KB
    __shared__ float  Os[4][32][OSP];    // 18.4 KB, wave-private slices

    const int t    = threadIdx.x;
    const int wave = t >> 6;
    const int lane = t & 63;
    const int lr   = lane & 15;
    const int quad = lane >> 4;
    const int wm   = wave * 32;          // q offset of wave within 128-tile

    // ---- Q fragments -> registers, held all kernel ----
    // af[ks][mi]: q = qt*128 + wm + mi*16 + lr, d = ks*32 + quad*8 .. +7
    bf16x8 af[4][2];
    {
        const float* Qb = Qg + ((size_t)(qt * 128 + wm + lr) * HM + g) * DD + quad * 8;
#pragma unroll
        for (int mi = 0; mi < 2; ++mi) {
            const float* qr = Qb + (size_t)mi * 16 * HM * DD;
#pragma unroll
            for (int ks = 0; ks < 4; ++ks) {
                float4 a = *(const float4*)(qr + ks * 32);
                float4 b = *(const float4*)(qr + ks * 32 + 4);
                af[ks][mi] = (bf16x8){ (__bf16)a.x, (__bf16)a.y, (__bf16)a.z, (__bf16)a.w,
                                       (__bf16)b.x, (__bf16)b.y, (__bf16)b.z, (__bf16)b.w };
            }
        }
    }

    // ---- stage K tile 0 (rows kh*512 .. +31), coalesced ----
    const float* Kbase = Kg + ((size_t)kh * 512) * (HM * DD) + (size_t)g * DD;
#pragma unroll
    for (int j = 0; j < 4; ++j) {
        int c = t + 256 * j;             // 0..1023
        int row = c >> 5, c4 = c & 31;
        float4 b = *(const float4*)(Kbase + (size_t)row * (HM * DD) + c4 * 4);
        bf16x4 bv = { (__bf16)b.x, (__bf16)b.y, (__bf16)b.z, (__bf16)b.w };
        *(bf16x4*)&Ks[0][row][c4 * 4] = bv;
    }
    __syncthreads();

    const size_t obase = (size_t)g * QL * 1025;

    for (int kt = 0; kt < 16; ++kt) {
        const int b = kt & 1;

        // ---- issue next K tile loads early (hidden under MFMA+epilogue) ----
        float4 nf[4];
        if (kt < 15) {
            const float* nb = Kbase + (size_t)((kt + 1) * 32) * (HM * DD);
#pragma unroll
            for (int j = 0; j < 4; ++j) {
                int c = t + 256 * j;
                nf[j] = *(const float4*)(nb + (size_t)(c >> 5) * (HM * DD) + (c & 31) * 4);
            }
        }

        // ---- MFMA: wave computes 32q x 32k, swapped operands mfma(K,Q) ----
        floatx4 acc[2][2] = {};
#pragma unroll
        for (int ks = 0; ks < 4; ++ks) {
            const int d0 = ks * 32 + quad * 8;
            bf16x8 kf[2];
#pragma unroll
            for (int ni = 0; ni < 2; ++ni)
                kf[ni] = *(const bf16x8*)&Ks[b][ni * 16 + lr][d0];
#pragma unroll
            for (int mi = 0; mi < 2; ++mi)
#pragma unroll
                for (int ni = 0; ni < 2; ++ni)
                    acc[mi][ni] = __builtin_amdgcn_mfma_f32_16x16x32_bf16(
                        kf[ni], af[ks][mi], acc[mi][ni], 0, 0, 0);
        }

        // ---- park accs in wave-private LDS tile (no barrier needed) ----
        // col=lane&15 -> q(lr), row=quad*4+r -> k
#pragma unroll
        for (int mi = 0; mi < 2; ++mi)
#pragma unroll
            for (int ni = 0; ni < 2; ++ni)
                *(floatx4*)&Os[wave][mi * 16 + lr][ni * 16 + quad * 4] = acc[mi][ni];

        // ---- readback flat: 8 rows x 128 B contiguous per instruction ----
#pragma unroll
        for (int j = 0; j < 4; ++j) {
            int c = lane + 64 * j;           // 0..255
            int row = c >> 3, col = (c & 7) * 4;
            floatx4 v = *(const floatx4*)&Os[wave][row][col];
            const int q  = (qt << 7) + wm + row;
            const int k0 = (kh << 9) + (kt << 5) + col;
            floatx4 mv = *(const floatx4*)(mask + ((size_t)q << 10) + k0);
            v = v * SM_SCALE + mv;
            *(floatx4u*)(out + obase + (size_t)q * 1025 + k0) = v;
        }

        // ---- convert + write next K tile, one barrier per iteration ----
        if (kt < 15) {
#pragma unroll
            for (int j = 0; j < 4; ++j) {
                int c = t + 256 * j;
                bf16x4 bv = { (__bf16)nf[j].x, (__bf16)nf[j].y,
                              (__bf16)nf[j].z, (__bf16)nf[j].w };
                *(bf16x4*)&Ks[1 - b][c >> 5][(c & 31) * 4] = bv;
            }
            __syncthreads();
        }
    }

    // ---- fused sink column (kh==1 blocks only) ----
    if (kh == 1 && t < 128) {
        const int q = (qt << 7) + t;
        out[obase + (size_t)q * 1025 + 1024] = sinks[((size_t)g << 10) + q];
    }
}

extern "C" void kernel_launch(void* const* d_in, const int* in_sizes, int n_in,
                              void* d_out, int out_size, void* d_ws, size_t ws_size,
                              hipStream_t stream)
{
    const float* Q     = (const float*)d_in[0];
    const float* K     = (const float*)d_in[1];
    const float* mask  = (const float*)d_in[2];
    const float* sinks = (const float*)d_in[3];
    float* out = (float*)d_out;

    qk7_kernel<<<1024, 256, 0, stream>>>(Q, K, mask, sinks, out);
}